// Round 17
// baseline (424.505 us; speedup 1.0000x reference)
//
#include <hip/hip_runtime.h>
#include <hip/hip_bf16.h>

// Problem constants (reference: T=8192, H=1024, I=2816, E=8)
#define T_TOK 8192
#define H_DIM 1024
#define I_DIM 2816
#define E_EXP 8

#define MAXT (T_TOK / 256 + E_EXP) // 40 worst-case BM=256 tiles
#define GU_COLS 22                 // virtual-W rows 2*I=5632, BN=256 -> 22
#define DN_COLS 4                  // H=1024, BN=256 -> 4 col-blocks
#define DN_SPLIT 2                 // split-K over I (44+44 K-tiles)

typedef __bf16 bf16x8 __attribute__((ext_vector_type(8)));
typedef float f32x4 __attribute__((ext_vector_type(4)));

__device__ __forceinline__ void gload16(const void* g, void* l) {
  __builtin_amdgcn_global_load_lds((const __attribute__((address_space(1))) void*)g,
                                   (__attribute__((address_space(3))) void*)l, 16, 0, 0);
}

__device__ __forceinline__ bf16x8 cvt8(const float4& p0, const float4& p1) {
  bf16x8 v;
  v[0] = (__bf16)p0.x; v[1] = (__bf16)p0.y; v[2] = (__bf16)p0.z; v[3] = (__bf16)p0.w;
  v[4] = (__bf16)p1.x; v[5] = (__bf16)p1.y; v[6] = (__bf16)p1.z; v[7] = (__bf16)p1.w;
  return v;
}

// bijective XCD-chunk swizzle (m204)
__device__ __forceinline__ int xcd_swizzle(int id, int nwg) {
  const int q = nwg >> 3, r = nwg & 7;
  const int xcd = id & 7, j = id >> 3;
  return (xcd < r ? xcd * (q + 1) : r * (q + 1) + (xcd - r) * q) + j;
}

#define FENCE() asm volatile("" ::: "memory")
#define BARRIER() do { __builtin_amdgcn_s_barrier(); FENCE(); } while (0)

// BK=32 LDS tile [rows][64B]; chunk swizzle c ^= (row>>1)&3 (validated r8/r12)
__device__ __forceinline__ int swz32(int row, int kc) {
  return row * 64 + (kc ^ (((row >> 1) & 3) << 4));
}

// ---------------- bucketing kernels ----------------
__global__ void k_count(const int* __restrict__ idx, int* __restrict__ counts) {
  int t = blockIdx.x * blockDim.x + threadIdx.x;
  if (t < T_TOK) atomicAdd(&counts[idx[t]], 1);
}

__global__ void k_tilesB(const int* __restrict__ counts, int* __restrict__ offsets,
                         int* __restrict__ tE, int* __restrict__ tB,
                         int* __restrict__ tEnd, int* __restrict__ nT) {
  if (threadIdx.x != 0 || blockIdx.x != 0) return;
  int off = 0, nt = 0;
  for (int e = 0; e < E_EXP; ++e) {
    offsets[e] = off;
    int c = counts[e];
    for (int b = 0; b < c; b += 256) { tE[nt] = e; tB[nt] = off + b; tEnd[nt] = off + c; ++nt; }
    off += c;
  }
  offsets[E_EXP] = off;
  *nT = nt;
}

__global__ void k_scatter(const int* __restrict__ idx, const int* __restrict__ offsets,
                          int* __restrict__ cursor, int* __restrict__ order) {
  int t = blockIdx.x * blockDim.x + threadIdx.x;
  if (t < T_TOK) {
    int e = idx[t];
    int p = offsets[e] + atomicAdd(&cursor[e], 1);
    order[p] = t;
  }
}

// ---------------- conversions ----------------
__global__ __launch_bounds__(256) void k_cvt(const float* __restrict__ src,
                                             __bf16* __restrict__ dst, int n8) {
  int i = blockIdx.x * blockDim.x + threadIdx.x;
  if (i < n8) {
    const float4 p0 = ((const float4*)src)[i * 2];
    const float4 p1 = ((const float4*)src)[i * 2 + 1];
    ((bf16x8*)dst)[i] = cvt8(p0, p1);
  }
}

// Wg,Wu -> row-interleaved virtual W (per 32 vrows: 16 gate + 16 up), bf16
__global__ __launch_bounds__(128) void k_cvtgu(const float* __restrict__ Wg,
                                               const float* __restrict__ Wu,
                                               __bf16* __restrict__ wgu) {
  const int b = blockIdx.x; // e*I + i
  const int e = b / I_DIM, i = b - e * I_DIM;
  const int vg = ((i >> 4) << 5) + (i & 15);
  const size_t sb = ((size_t)e * I_DIM + i) * H_DIM + threadIdx.x * 8;
  const size_t db = ((size_t)e * (2 * I_DIM) + vg) * H_DIM + threadIdx.x * 8;
  const float4 g0 = *(const float4*)(Wg + sb);
  const float4 g1 = *(const float4*)(Wg + sb + 4);
  *(bf16x8*)(wgu + db) = cvt8(g0, g1);
  const float4 u0 = *(const float4*)(Wu + sb);
  const float4 u1 = *(const float4*)(Wu + sb + 4);
  *(bf16x8*)(wgu + db + (size_t)16 * H_DIM) = cvt8(u0, u1);
}

// gather by order + convert x -> xp (bf16, permuted rows)
__global__ __launch_bounds__(128) void k_xperm(const float* __restrict__ x,
                                               const int* __restrict__ order,
                                               __bf16* __restrict__ xp) {
  const int row = blockIdx.x;
  const int tok = order[row];
  const float* s = x + (size_t)tok * H_DIM + threadIdx.x * 8;
  const float4 p0 = ((const float4*)s)[0];
  const float4 p1 = ((const float4*)s)[1];
  *(bf16x8*)(xp + (size_t)row * H_DIM + threadIdx.x * 8) = cvt8(p0, p1);
}

// =====================================================================
// pass 2 (unchanged from r16, passed): fused gate/up GEMM + silu*mul -> hp
// BM=256 x BNv=256, BK=32, nK=32. 4-buffer LDS ring (128KB), lookahead 3.
// =====================================================================
__global__ __launch_bounds__(512) void k_gateup14(
    const __bf16* __restrict__ xp, const __bf16* __restrict__ wgu,
    const int* __restrict__ tE, const int* __restrict__ tB,
    const int* __restrict__ tEnd, const int* __restrict__ nT, __bf16* __restrict__ hp) {
  const int nwg = *nT * GU_COLS;
  const int id = blockIdx.x;
  if (id >= nwg) return;
  const int wgid = xcd_swizzle(id, nwg);
  const int tile = wgid / GU_COLS;
  const int col = wgid - tile * GU_COLS;
  const int e = tE[tile];
  const int rowbase = tB[tile];
  const int rowEnd = tEnd[tile];

  extern __shared__ __align__(16) unsigned char smem[];

  const int tid = threadIdx.x;
  const int lane = tid & 63;
  const int w = tid >> 6;
  const int wm = w >> 2, wn = w & 3; // 2M x 4N; wave tile 128 x 64

  const int srow = tid >> 2;
  const int sch = (tid & 3) ^ ((tid >> 3) & 3);
  const __bf16* aS0 = xp + (size_t)(rowbase + srow) * H_DIM + sch * 8;
  const __bf16* aS1 = aS0 + (size_t)128 * H_DIM;
  const __bf16* wS0 = wgu + ((size_t)e * (2 * I_DIM) + col * 256 + srow) * H_DIM + sch * 8;
  const __bf16* wS1 = wS0 + (size_t)128 * H_DIM;
  const int ldst = tid * 16;

  const int l15 = lane & 15;
  const int kc = (lane >> 4) << 4;
  int aoff[8], boff[4];
#pragma unroll
  for (int m = 0; m < 8; ++m) {
    const int grow = wm * 128 + m * 16 + l15;
    aoff[m] = swz32(grow, kc);
  }
#pragma unroll
  for (int n = 0; n < 4; ++n) {
    const int vr = wn * 64 + n * 16 + l15;
    boff[n] = 16384 + swz32(vr, kc);
  }

  f32x4 acc[8][4];
#pragma unroll
  for (int m = 0; m < 8; ++m)
#pragma unroll
    for (int n = 0; n < 4; ++n)
#pragma unroll
      for (int j = 0; j < 4; ++j) acc[m][n][j] = 0.f;

  auto SH = [&](int k) {
    unsigned char* b = smem + (k & 3) * 32768;
    const size_t ko = (size_t)k * 32;
    gload16(aS0 + ko, b + ldst);
    gload16(aS1 + ko, b + 8192 + ldst);
    gload16(wS0 + ko, b + 16384 + ldst);
    gload16(wS1 + ko, b + 24576 + ldst);
  };

  auto COMPUTE = [&](int k) {
    const unsigned char* B = smem + (k & 3) * 32768;
    bf16x8 aq[8], bq[4];
#pragma unroll
    for (int n = 0; n < 4; ++n) bq[n] = *(const bf16x8*)(B + boff[n]);
#pragma unroll
    for (int m = 0; m < 8; ++m) aq[m] = *(const bf16x8*)(B + aoff[m]);
    __builtin_amdgcn_s_setprio(1);
#pragma unroll
    for (int m = 0; m < 8; ++m)
#pragma unroll
      for (int n = 0; n < 4; ++n)
        acc[m][n] = __builtin_amdgcn_mfma_f32_16x16x32_bf16(aq[m], bq[n], acc[m][n], 0, 0, 0);
    __builtin_amdgcn_s_setprio(0);
  };

  const int nK = H_DIM / 32; // 32
  SH(0); SH(1); SH(2);

  for (int k = 0; k < nK - 2; ++k) {
    asm volatile("s_waitcnt vmcnt(8)" ::: "memory");
    BARRIER();
    if (k + 3 < nK) SH(k + 3);
    COMPUTE(k);
  }
  asm volatile("s_waitcnt vmcnt(4)" ::: "memory");
  BARRIER();
  COMPUTE(nK - 2);
  asm volatile("s_waitcnt vmcnt(0)" ::: "memory");
  BARRIER();
  COMPUTE(nK - 1);

#pragma unroll
  for (int m = 0; m < 8; ++m) {
    const int row0 = wm * 128 + m * 16 + ((lane >> 4) << 2);
#pragma unroll
    for (int j = 0; j < 4; ++j) {
      const int gr = rowbase + row0 + j;
      if (gr < rowEnd) {
        __bf16* dst = hp + (size_t)gr * I_DIM + col * 128 + wn * 32 + l15;
#pragma unroll
        for (int pq = 0; pq < 2; ++pq) {
          const float g = acc[m][2 * pq][j];
          const float u = acc[m][2 * pq + 1][j];
          dst[pq * 16] = (__bf16)(g / (1.f + __expf(-g)) * u);
        }
      }
    }
  }
}

// =====================================================================
// pass 3 (RESTRUCTURED): down GEMM, BM=256 x BN=256, split-K=2,
// f32 atomicAdd into out (out zeroed via memset at launch).
// Same r16-validated ring schedule: BK=32, 4-buffer (128KB), lookahead 3,
// vmcnt 8/4/0 tail peel, 4 gload16/thread/tile, 12 ds_read + 32 MFMA.
// A re-reads drop 8x -> 4x (369 -> 184 MB); grid = nT*4*2 <= 320.
// =====================================================================
__global__ __launch_bounds__(512) void k_down15(
    const __bf16* __restrict__ hp, const __bf16* __restrict__ wd,
    const int* __restrict__ order, const int* __restrict__ tE, const int* __restrict__ tB,
    const int* __restrict__ tEnd, const int* __restrict__ nT, float* __restrict__ out) {
  const int nwg = *nT * DN_COLS * DN_SPLIT;
  const int id = blockIdx.x;
  if (id >= nwg) return;
  const int wgid = xcd_swizzle(id, nwg);
  const int tile = wgid >> 3;          // /(4 cols * 2 splits)
  const int r = wgid & 7;
  const int col = r >> 1;              // 0..3 (256 H-cols each)
  const int split = r & 1;             // 0..1 (44 K-tiles each)
  const int e = tE[tile];
  const int rowbase = tB[tile];
  const int rowEnd = tEnd[tile];
  const int nbase = col * 256;

  extern __shared__ __align__(16) unsigned char smem2[];
  // per buffer (32KB): A rows 0..255 [16KB] then W hrows 0..255 [16KB]

  const int tid = threadIdx.x;
  const int lane = tid & 63;
  const int w = tid >> 6;
  const int wm = w >> 2, wn = w & 3; // 2M x 4N; wave tile 128 x 64

  const int srow = tid >> 2;
  const int sch = (tid & 3) ^ ((tid >> 3) & 3);
  const __bf16* aS0 = hp + (size_t)(rowbase + srow) * I_DIM + sch * 8;
  const __bf16* aS1 = aS0 + (size_t)128 * I_DIM;
  const __bf16* wS0 = wd + ((size_t)e * H_DIM + nbase + srow) * I_DIM + sch * 8;
  const __bf16* wS1 = wS0 + (size_t)128 * I_DIM;
  const int ldst = tid * 16;

  const int l15 = lane & 15;
  const int kc = (lane >> 4) << 4;
  int aoff[8], boff[4];
#pragma unroll
  for (int m = 0; m < 8; ++m) {
    const int grow = wm * 128 + m * 16 + l15;
    aoff[m] = swz32(grow, kc);
  }
#pragma unroll
  for (int n = 0; n < 4; ++n) {
    const int hr = wn * 64 + n * 16 + l15; // 0..255 (local H row)
    boff[n] = 16384 + swz32(hr, kc);
  }

  f32x4 acc[8][4];
#pragma unroll
  for (int m = 0; m < 8; ++m)
#pragma unroll
    for (int n = 0; n < 4; ++n)
#pragma unroll
      for (int j = 0; j < 4; ++j) acc[m][n][j] = 0.f;

  const int kt0 = split * 44; // global K-tile base for this split

  auto SH = [&](int k) { // k = local tile index 0..43
    unsigned char* b = smem2 + (k & 3) * 32768;
    const size_t ko = (size_t)(kt0 + k) * 32;
    gload16(aS0 + ko, b + ldst);
    gload16(aS1 + ko, b + 8192 + ldst);
    gload16(wS0 + ko, b + 16384 + ldst);
    gload16(wS1 + ko, b + 24576 + ldst);
  };

  auto COMPUTE = [&](int k) {
    const unsigned char* B = smem2 + (k & 3) * 32768;
    bf16x8 aq[8], bq[4];
#pragma unroll
    for (int n = 0; n < 4; ++n) bq[n] = *(const bf16x8*)(B + boff[n]);
#pragma unroll
    for (int m = 0; m < 8; ++m) aq[m] = *(const bf16x8*)(B + aoff[m]);
    __builtin_amdgcn_s_setprio(1);
#pragma unroll
    for (int m = 0; m < 8; ++m)
#pragma unroll
      for (int n = 0; n < 4; ++n)
        acc[m][n] = __builtin_amdgcn_mfma_f32_16x16x32_bf16(aq[m], bq[n], acc[m][n], 0, 0, 0);
    __builtin_amdgcn_s_setprio(0);
  };

  const int nK = (I_DIM / 32) / DN_SPLIT; // 44
  SH(0); SH(1); SH(2);

  for (int k = 0; k < nK - 2; ++k) {
    asm volatile("s_waitcnt vmcnt(8)" ::: "memory");
    BARRIER();
    if (k + 3 < nK) SH(k + 3);
    COMPUTE(k);
  }
  asm volatile("s_waitcnt vmcnt(4)" ::: "memory");
  BARRIER();
  COMPUTE(nK - 2);
  asm volatile("s_waitcnt vmcnt(0)" ::: "memory");
  BARRIER();
  COMPUTE(nK - 1);

  // epilogue: atomic-accumulate rows into out[token] (out pre-zeroed)
#pragma unroll
  for (int m = 0; m < 8; ++m) {
    const int row0 = wm * 128 + m * 16 + ((lane >> 4) << 2);
#pragma unroll
    for (int j = 0; j < 4; ++j) {
      const int gr = rowbase + row0 + j;
      if (gr < rowEnd) {
        const int tok = order[gr];
        float* dst = out + (size_t)tok * H_DIM + nbase;
#pragma unroll
        for (int n = 0; n < 4; ++n) {
          const int c2 = wn * 64 + n * 16 + l15;
          atomicAdd(&dst[c2], acc[m][n][j]);
        }
      }
    }
  }
}

// ---------------- launch ----------------
extern "C" void kernel_launch(void* const* d_in, const int* in_sizes, int n_in,
                              void* d_out, int out_size, void* d_ws, size_t ws_size,
                              hipStream_t stream) {
  const float* x = (const float*)d_in[0];
  const int* eidx = (const int*)d_in[1];
  const float* Wg = (const float*)d_in[2];
  const float* Wu = (const float*)d_in[3];
  const float* Wd = (const float*)d_in[4];
  float* out = (float*)d_out;

  char* ws = (char*)d_ws;
  size_t off = 0;
  auto alloc = [&](size_t bytes) -> void* {
    void* p = ws + off;
    off = (off + bytes + 255) & ~(size_t)255;
    return p;
  };
  const size_t TPAD = T_TOK + 256;
  __bf16* hp = (__bf16*)alloc(TPAD * I_DIM * sizeof(__bf16));
  int* order = (int*)alloc(T_TOK * sizeof(int));
  int* offsets = (int*)alloc((E_EXP + 1) * sizeof(int));
  int* tE = (int*)alloc(MAXT * sizeof(int));
  int* tB = (int*)alloc(MAXT * sizeof(int));
  int* tEnd = (int*)alloc(MAXT * sizeof(int));
  int* nT = (int*)alloc(sizeof(int));
  int* cc = (int*)alloc(2 * E_EXP * sizeof(int));
  int* counts = cc;
  int* cursor = cc + E_EXP;

  const size_t WSZ = (size_t)E_EXP * I_DIM * H_DIM;
  __bf16* xp = (__bf16*)alloc(TPAD * H_DIM * sizeof(__bf16));
  __bf16* wgu16 = (__bf16*)alloc(2 * WSZ * sizeof(__bf16));
  __bf16* wd16 = (__bf16*)alloc(WSZ * sizeof(__bf16));

  hipFuncSetAttribute((const void*)k_gateup14,
                      hipFuncAttributeMaxDynamicSharedMemorySize, 131072);
  hipFuncSetAttribute((const void*)k_down15,
                      hipFuncAttributeMaxDynamicSharedMemorySize, 131072);

  hipMemsetAsync(cc, 0, 2 * E_EXP * sizeof(int), stream);
  hipMemsetAsync(out, 0, (size_t)T_TOK * H_DIM * sizeof(float), stream); // split-K accum base
  k_count<<<T_TOK / 256, 256, 0, stream>>>(eidx, counts);
  k_tilesB<<<1, 1, 0, stream>>>(counts, offsets, tE, tB, tEnd, nT);
  k_scatter<<<T_TOK / 256, 256, 0, stream>>>(eidx, offsets, cursor, order);

  k_cvtgu<<<E_EXP * I_DIM, 128, 0, stream>>>(Wg, Wu, wgu16);
  const int n8 = (int)(WSZ / 8);
  k_cvt<<<(n8 + 255) / 256, 256, 0, stream>>>(Wd, wd16, n8);
  k_xperm<<<T_TOK, 128, 0, stream>>>(x, order, xp);

  k_gateup14<<<MAXT * GU_COLS, 512, 131072, stream>>>(xp, wgu16, tE, tB, tEnd, nT, hp);
  k_down15<<<MAXT * DN_COLS * DN_SPLIT, 512, 131072, stream>>>(hp, wd16, order, tE, tB, tEnd, nT, out);
}

// Round 18
// 389.759 us; speedup vs baseline: 1.0891x; 1.0891x over previous
//
#include <hip/hip_runtime.h>
#include <hip/hip_bf16.h>

// Problem constants (reference: T=8192, H=1024, I=2816, E=8)
#define T_TOK 8192
#define H_DIM 1024
#define I_DIM 2816
#define E_EXP 8

#define MAXT (T_TOK / 256 + E_EXP) // 40 worst-case BM=256 tiles
#define GU_COLS 22                 // virtual-W rows 2*I=5632, BN=256 -> 22
#define DN_COLS 4                  // H=1024, BN=256 -> 4 col-blocks
#define DN_SPLIT 2                 // split-K over I (44+44 K-tiles)

typedef __bf16 bf16x8 __attribute__((ext_vector_type(8)));
typedef float f32x4 __attribute__((ext_vector_type(4)));

__device__ __forceinline__ void gload16(const void* g, void* l) {
  __builtin_amdgcn_global_load_lds((const __attribute__((address_space(1))) void*)g,
                                   (__attribute__((address_space(3))) void*)l, 16, 0, 0);
}

__device__ __forceinline__ bf16x8 cvt8(const float4& p0, const float4& p1) {
  bf16x8 v;
  v[0] = (__bf16)p0.x; v[1] = (__bf16)p0.y; v[2] = (__bf16)p0.z; v[3] = (__bf16)p0.w;
  v[4] = (__bf16)p1.x; v[5] = (__bf16)p1.y; v[6] = (__bf16)p1.z; v[7] = (__bf16)p1.w;
  return v;
}

// bijective XCD-chunk swizzle (m204)
__device__ __forceinline__ int xcd_swizzle(int id, int nwg) {
  const int q = nwg >> 3, r = nwg & 7;
  const int xcd = id & 7, j = id >> 3;
  return (xcd < r ? xcd * (q + 1) : r * (q + 1) + (xcd - r) * q) + j;
}

#define FENCE() asm volatile("" ::: "memory")
#define BARRIER() do { __builtin_amdgcn_s_barrier(); FENCE(); } while (0)

// BK=32 LDS tile [rows][64B]; chunk swizzle c ^= (row>>1)&3 (validated r8/r12)
__device__ __forceinline__ int swz32(int row, int kc) {
  return row * 64 + (kc ^ (((row >> 1) & 3) << 4));
}

// ---------------- bucketing kernels ----------------
__global__ void k_count(const int* __restrict__ idx, int* __restrict__ counts) {
  int t = blockIdx.x * blockDim.x + threadIdx.x;
  if (t < T_TOK) atomicAdd(&counts[idx[t]], 1);
}

__global__ void k_tilesB(const int* __restrict__ counts, int* __restrict__ offsets,
                         int* __restrict__ tE, int* __restrict__ tB,
                         int* __restrict__ tEnd, int* __restrict__ nT) {
  if (threadIdx.x != 0 || blockIdx.x != 0) return;
  int off = 0, nt = 0;
  for (int e = 0; e < E_EXP; ++e) {
    offsets[e] = off;
    int c = counts[e];
    for (int b = 0; b < c; b += 256) { tE[nt] = e; tB[nt] = off + b; tEnd[nt] = off + c; ++nt; }
    off += c;
  }
  offsets[E_EXP] = off;
  *nT = nt;
}

__global__ void k_scatter(const int* __restrict__ idx, const int* __restrict__ offsets,
                          int* __restrict__ cursor, int* __restrict__ order) {
  int t = blockIdx.x * blockDim.x + threadIdx.x;
  if (t < T_TOK) {
    int e = idx[t];
    int p = offsets[e] + atomicAdd(&cursor[e], 1);
    order[p] = t;
  }
}

// ---------------- conversions ----------------
__global__ __launch_bounds__(256) void k_cvt(const float* __restrict__ src,
                                             __bf16* __restrict__ dst, int n8) {
  int i = blockIdx.x * blockDim.x + threadIdx.x;
  if (i < n8) {
    const float4 p0 = ((const float4*)src)[i * 2];
    const float4 p1 = ((const float4*)src)[i * 2 + 1];
    ((bf16x8*)dst)[i] = cvt8(p0, p1);
  }
}

// Wg,Wu -> row-interleaved virtual W (per 32 vrows: 16 gate + 16 up), bf16
__global__ __launch_bounds__(128) void k_cvtgu(const float* __restrict__ Wg,
                                               const float* __restrict__ Wu,
                                               __bf16* __restrict__ wgu) {
  const int b = blockIdx.x; // e*I + i
  const int e = b / I_DIM, i = b - e * I_DIM;
  const int vg = ((i >> 4) << 5) + (i & 15);
  const size_t sb = ((size_t)e * I_DIM + i) * H_DIM + threadIdx.x * 8;
  const size_t db = ((size_t)e * (2 * I_DIM) + vg) * H_DIM + threadIdx.x * 8;
  const float4 g0 = *(const float4*)(Wg + sb);
  const float4 g1 = *(const float4*)(Wg + sb + 4);
  *(bf16x8*)(wgu + db) = cvt8(g0, g1);
  const float4 u0 = *(const float4*)(Wu + sb);
  const float4 u1 = *(const float4*)(Wu + sb + 4);
  *(bf16x8*)(wgu + db + (size_t)16 * H_DIM) = cvt8(u0, u1);
}

// gather by order + convert x -> xp (bf16, permuted rows)
__global__ __launch_bounds__(128) void k_xperm(const float* __restrict__ x,
                                               const int* __restrict__ order,
                                               __bf16* __restrict__ xp) {
  const int row = blockIdx.x;
  const int tok = order[row];
  const float* s = x + (size_t)tok * H_DIM + threadIdx.x * 8;
  const float4 p0 = ((const float4*)s)[0];
  const float4 p1 = ((const float4*)s)[1];
  *(bf16x8*)(xp + (size_t)row * H_DIM + threadIdx.x * 8) = cvt8(p0, p1);
}

// out += part (split-K reduction), float4 grid-stride
__global__ __launch_bounds__(256) void k_add(float* __restrict__ out,
                                             const float* __restrict__ part, int n4) {
  for (int i = blockIdx.x * blockDim.x + threadIdx.x; i < n4; i += gridDim.x * blockDim.x) {
    float4 a = ((float4*)out)[i];
    const float4 b = ((const float4*)part)[i];
    a.x += b.x; a.y += b.y; a.z += b.z; a.w += b.w;
    ((float4*)out)[i] = a;
  }
}

// =====================================================================
// pass 2 (unchanged from r16/r17, passed): fused gate/up GEMM + silu*mul -> hp
// BM=256 x BNv=256, BK=32, nK=32. 4-buffer LDS ring (128KB), lookahead 3.
// =====================================================================
__global__ __launch_bounds__(512) void k_gateup14(
    const __bf16* __restrict__ xp, const __bf16* __restrict__ wgu,
    const int* __restrict__ tE, const int* __restrict__ tB,
    const int* __restrict__ tEnd, const int* __restrict__ nT, __bf16* __restrict__ hp) {
  const int nwg = *nT * GU_COLS;
  const int id = blockIdx.x;
  if (id >= nwg) return;
  const int wgid = xcd_swizzle(id, nwg);
  const int tile = wgid / GU_COLS;
  const int col = wgid - tile * GU_COLS;
  const int e = tE[tile];
  const int rowbase = tB[tile];
  const int rowEnd = tEnd[tile];

  extern __shared__ __align__(16) unsigned char smem[];

  const int tid = threadIdx.x;
  const int lane = tid & 63;
  const int w = tid >> 6;
  const int wm = w >> 2, wn = w & 3; // 2M x 4N; wave tile 128 x 64

  const int srow = tid >> 2;
  const int sch = (tid & 3) ^ ((tid >> 3) & 3);
  const __bf16* aS0 = xp + (size_t)(rowbase + srow) * H_DIM + sch * 8;
  const __bf16* aS1 = aS0 + (size_t)128 * H_DIM;
  const __bf16* wS0 = wgu + ((size_t)e * (2 * I_DIM) + col * 256 + srow) * H_DIM + sch * 8;
  const __bf16* wS1 = wS0 + (size_t)128 * H_DIM;
  const int ldst = tid * 16;

  const int l15 = lane & 15;
  const int kc = (lane >> 4) << 4;
  int aoff[8], boff[4];
#pragma unroll
  for (int m = 0; m < 8; ++m) {
    const int grow = wm * 128 + m * 16 + l15;
    aoff[m] = swz32(grow, kc);
  }
#pragma unroll
  for (int n = 0; n < 4; ++n) {
    const int vr = wn * 64 + n * 16 + l15;
    boff[n] = 16384 + swz32(vr, kc);
  }

  f32x4 acc[8][4];
#pragma unroll
  for (int m = 0; m < 8; ++m)
#pragma unroll
    for (int n = 0; n < 4; ++n)
#pragma unroll
      for (int j = 0; j < 4; ++j) acc[m][n][j] = 0.f;

  auto SH = [&](int k) {
    unsigned char* b = smem + (k & 3) * 32768;
    const size_t ko = (size_t)k * 32;
    gload16(aS0 + ko, b + ldst);
    gload16(aS1 + ko, b + 8192 + ldst);
    gload16(wS0 + ko, b + 16384 + ldst);
    gload16(wS1 + ko, b + 24576 + ldst);
  };

  auto COMPUTE = [&](int k) {
    const unsigned char* B = smem + (k & 3) * 32768;
    bf16x8 aq[8], bq[4];
#pragma unroll
    for (int n = 0; n < 4; ++n) bq[n] = *(const bf16x8*)(B + boff[n]);
#pragma unroll
    for (int m = 0; m < 8; ++m) aq[m] = *(const bf16x8*)(B + aoff[m]);
    __builtin_amdgcn_s_setprio(1);
#pragma unroll
    for (int m = 0; m < 8; ++m)
#pragma unroll
      for (int n = 0; n < 4; ++n)
        acc[m][n] = __builtin_amdgcn_mfma_f32_16x16x32_bf16(aq[m], bq[n], acc[m][n], 0, 0, 0);
    __builtin_amdgcn_s_setprio(0);
  };

  const int nK = H_DIM / 32; // 32
  SH(0); SH(1); SH(2);

  for (int k = 0; k < nK - 2; ++k) {
    asm volatile("s_waitcnt vmcnt(8)" ::: "memory");
    BARRIER();
    if (k + 3 < nK) SH(k + 3);
    COMPUTE(k);
  }
  asm volatile("s_waitcnt vmcnt(4)" ::: "memory");
  BARRIER();
  COMPUTE(nK - 2);
  asm volatile("s_waitcnt vmcnt(0)" ::: "memory");
  BARRIER();
  COMPUTE(nK - 1);

#pragma unroll
  for (int m = 0; m < 8; ++m) {
    const int row0 = wm * 128 + m * 16 + ((lane >> 4) << 2);
#pragma unroll
    for (int j = 0; j < 4; ++j) {
      const int gr = rowbase + row0 + j;
      if (gr < rowEnd) {
        __bf16* dst = hp + (size_t)gr * I_DIM + col * 128 + wn * 32 + l15;
#pragma unroll
        for (int pq = 0; pq < 2; ++pq) {
          const float g = acc[m][2 * pq][j];
          const float u = acc[m][2 * pq + 1][j];
          dst[pq * 16] = (__bf16)(g / (1.f + __expf(-g)) * u);
        }
      }
    }
  }
}

// =====================================================================
// pass 3: down GEMM, BM=256 x BN=256, split-K=2, NO ATOMICS:
// split 0 stores to out, split 1 stores to part (f32, aliases dead wgu),
// then k_add folds part into out. GEMM body = r17-validated ring schedule
// (BK=32, 4-buffer 128KB, lookahead 3, vmcnt 8/4/0 tail peel).
// =====================================================================
__global__ __launch_bounds__(512) void k_down16(
    const __bf16* __restrict__ hp, const __bf16* __restrict__ wd,
    const int* __restrict__ order, const int* __restrict__ tE, const int* __restrict__ tB,
    const int* __restrict__ tEnd, const int* __restrict__ nT,
    float* __restrict__ out, float* __restrict__ part) {
  const int nwg = *nT * DN_COLS * DN_SPLIT;
  const int id = blockIdx.x;
  if (id >= nwg) return;
  const int wgid = xcd_swizzle(id, nwg);
  const int tile = wgid >> 3;          // /(4 cols * 2 splits)
  const int r = wgid & 7;
  const int col = r >> 1;              // 0..3 (256 H-cols each)
  const int split = r & 1;             // 0..1 (44 K-tiles each)
  const int e = tE[tile];
  const int rowbase = tB[tile];
  const int rowEnd = tEnd[tile];
  const int nbase = col * 256;

  extern __shared__ __align__(16) unsigned char smem2[];
  // per buffer (32KB): A rows 0..255 [16KB] then W hrows 0..255 [16KB]

  const int tid = threadIdx.x;
  const int lane = tid & 63;
  const int w = tid >> 6;
  const int wm = w >> 2, wn = w & 3; // 2M x 4N; wave tile 128 x 64

  const int srow = tid >> 2;
  const int sch = (tid & 3) ^ ((tid >> 3) & 3);
  const __bf16* aS0 = hp + (size_t)(rowbase + srow) * I_DIM + sch * 8;
  const __bf16* aS1 = aS0 + (size_t)128 * I_DIM;
  const __bf16* wS0 = wd + ((size_t)e * H_DIM + nbase + srow) * I_DIM + sch * 8;
  const __bf16* wS1 = wS0 + (size_t)128 * I_DIM;
  const int ldst = tid * 16;

  const int l15 = lane & 15;
  const int kc = (lane >> 4) << 4;
  int aoff[8], boff[4];
#pragma unroll
  for (int m = 0; m < 8; ++m) {
    const int grow = wm * 128 + m * 16 + l15;
    aoff[m] = swz32(grow, kc);
  }
#pragma unroll
  for (int n = 0; n < 4; ++n) {
    const int hr = wn * 64 + n * 16 + l15; // 0..255 (local H row)
    boff[n] = 16384 + swz32(hr, kc);
  }

  f32x4 acc[8][4];
#pragma unroll
  for (int m = 0; m < 8; ++m)
#pragma unroll
    for (int n = 0; n < 4; ++n)
#pragma unroll
      for (int j = 0; j < 4; ++j) acc[m][n][j] = 0.f;

  const int kt0 = split * 44; // global K-tile base for this split

  auto SH = [&](int k) { // k = local tile index 0..43
    unsigned char* b = smem2 + (k & 3) * 32768;
    const size_t ko = (size_t)(kt0 + k) * 32;
    gload16(aS0 + ko, b + ldst);
    gload16(aS1 + ko, b + 8192 + ldst);
    gload16(wS0 + ko, b + 16384 + ldst);
    gload16(wS1 + ko, b + 24576 + ldst);
  };

  auto COMPUTE = [&](int k) {
    const unsigned char* B = smem2 + (k & 3) * 32768;
    bf16x8 aq[8], bq[4];
#pragma unroll
    for (int n = 0; n < 4; ++n) bq[n] = *(const bf16x8*)(B + boff[n]);
#pragma unroll
    for (int m = 0; m < 8; ++m) aq[m] = *(const bf16x8*)(B + aoff[m]);
    __builtin_amdgcn_s_setprio(1);
#pragma unroll
    for (int m = 0; m < 8; ++m)
#pragma unroll
      for (int n = 0; n < 4; ++n)
        acc[m][n] = __builtin_amdgcn_mfma_f32_16x16x32_bf16(aq[m], bq[n], acc[m][n], 0, 0, 0);
    __builtin_amdgcn_s_setprio(0);
  };

  const int nK = (I_DIM / 32) / DN_SPLIT; // 44
  SH(0); SH(1); SH(2);

  for (int k = 0; k < nK - 2; ++k) {
    asm volatile("s_waitcnt vmcnt(8)" ::: "memory");
    BARRIER();
    if (k + 3 < nK) SH(k + 3);
    COMPUTE(k);
  }
  asm volatile("s_waitcnt vmcnt(4)" ::: "memory");
  BARRIER();
  COMPUTE(nK - 2);
  asm volatile("s_waitcnt vmcnt(0)" ::: "memory");
  BARRIER();
  COMPUTE(nK - 1);

  // epilogue: plain stores — split 0 -> out, split 1 -> part (disjoint)
  float* base = (split == 0) ? out : part;
#pragma unroll
  for (int m = 0; m < 8; ++m) {
    const int row0 = wm * 128 + m * 16 + ((lane >> 4) << 2);
#pragma unroll
    for (int j = 0; j < 4; ++j) {
      const int gr = rowbase + row0 + j;
      if (gr < rowEnd) {
        const int tok = order[gr];
        float* dst = base + (size_t)tok * H_DIM + nbase;
#pragma unroll
        for (int n = 0; n < 4; ++n) {
          const int c2 = wn * 64 + n * 16 + l15;
          dst[c2] = acc[m][n][j];
        }
      }
    }
  }
}

// ---------------- launch ----------------
extern "C" void kernel_launch(void* const* d_in, const int* in_sizes, int n_in,
                              void* d_out, int out_size, void* d_ws, size_t ws_size,
                              hipStream_t stream) {
  const float* x = (const float*)d_in[0];
  const int* eidx = (const int*)d_in[1];
  const float* Wg = (const float*)d_in[2];
  const float* Wu = (const float*)d_in[3];
  const float* Wd = (const float*)d_in[4];
  float* out = (float*)d_out;

  char* ws = (char*)d_ws;
  size_t off = 0;
  auto alloc = [&](size_t bytes) -> void* {
    void* p = ws + off;
    off = (off + bytes + 255) & ~(size_t)255;
    return p;
  };
  const size_t TPAD = T_TOK + 256;
  __bf16* hp = (__bf16*)alloc(TPAD * I_DIM * sizeof(__bf16));
  int* order = (int*)alloc(T_TOK * sizeof(int));
  int* offsets = (int*)alloc((E_EXP + 1) * sizeof(int));
  int* tE = (int*)alloc(MAXT * sizeof(int));
  int* tB = (int*)alloc(MAXT * sizeof(int));
  int* tEnd = (int*)alloc(MAXT * sizeof(int));
  int* nT = (int*)alloc(sizeof(int));
  int* cc = (int*)alloc(2 * E_EXP * sizeof(int));
  int* counts = cc;
  int* cursor = cc + E_EXP;

  const size_t WSZ = (size_t)E_EXP * I_DIM * H_DIM;
  __bf16* xp = (__bf16*)alloc(TPAD * H_DIM * sizeof(__bf16));
  __bf16* wgu16 = (__bf16*)alloc(2 * WSZ * sizeof(__bf16));
  __bf16* wd16 = (__bf16*)alloc(WSZ * sizeof(__bf16));

  // split-K partial buffer: ALIASES wgu16 (dead after k_gateup14 completes;
  // k_down16 launches after it on the same stream). 32MB < 92MB region.
  float* part = (float*)wgu16;

  hipFuncSetAttribute((const void*)k_gateup14,
                      hipFuncAttributeMaxDynamicSharedMemorySize, 131072);
  hipFuncSetAttribute((const void*)k_down16,
                      hipFuncAttributeMaxDynamicSharedMemorySize, 131072);

  hipMemsetAsync(cc, 0, 2 * E_EXP * sizeof(int), stream);
  k_count<<<T_TOK / 256, 256, 0, stream>>>(eidx, counts);
  k_tilesB<<<1, 1, 0, stream>>>(counts, offsets, tE, tB, tEnd, nT);
  k_scatter<<<T_TOK / 256, 256, 0, stream>>>(eidx, offsets, cursor, order);

  k_cvtgu<<<E_EXP * I_DIM, 128, 0, stream>>>(Wg, Wu, wgu16);
  const int n8 = (int)(WSZ / 8);
  k_cvt<<<(n8 + 255) / 256, 256, 0, stream>>>(Wd, wd16, n8);
  k_xperm<<<T_TOK, 128, 0, stream>>>(x, order, xp);

  k_gateup14<<<MAXT * GU_COLS, 512, 131072, stream>>>(xp, wgu16, tE, tB, tEnd, nT, hp);
  k_down16<<<MAXT * DN_COLS * DN_SPLIT, 512, 131072, stream>>>(hp, wd16, order, tE, tB, tEnd, nT, out, part);
  k_add<<<2048, 256, 0, stream>>>(out, part, T_TOK * H_DIM / 4);
}

// Round 19
// 366.356 us; speedup vs baseline: 1.1587x; 1.0639x over previous
//
#include <hip/hip_runtime.h>
#include <hip/hip_bf16.h>

// Problem constants (reference: T=8192, H=1024, I=2816, E=8)
#define T_TOK 8192
#define H_DIM 1024
#define I_DIM 2816
#define E_EXP 8

#define BK 64
#define MAXT (T_TOK / 256 + E_EXP) // 40 worst-case BM=256 tiles
#define GU_COLS (I_DIM / 128)      // 22
#define DN_COLS (H_DIM / 128)      // 8

typedef __bf16 bf16x8 __attribute__((ext_vector_type(8)));
typedef float f32x4 __attribute__((ext_vector_type(4)));

// swizzled LDS byte offset for a [rows][64 bf16] tile; row stride = 128B
#define SWZ(r, bc) (((r) * (BK * 2)) + (((bc) ^ (((r) & 7) << 4))))

__device__ __forceinline__ void gload16(const void* g, void* l) {
  __builtin_amdgcn_global_load_lds((const __attribute__((address_space(1))) void*)g,
                                   (__attribute__((address_space(3))) void*)l, 16, 0, 0);
}

__device__ __forceinline__ bf16x8 cvt8(const float4& p0, const float4& p1) {
  bf16x8 v;
  v[0] = (__bf16)p0.x; v[1] = (__bf16)p0.y; v[2] = (__bf16)p0.z; v[3] = (__bf16)p0.w;
  v[4] = (__bf16)p1.x; v[5] = (__bf16)p1.y; v[6] = (__bf16)p1.z; v[7] = (__bf16)p1.w;
  return v;
}

// bijective XCD-chunk swizzle (m204)
__device__ __forceinline__ int xcd_swizzle(int id, int nwg) {
  const int q = nwg >> 3, r = nwg & 7;
  const int xcd = id & 7, j = id >> 3;
  return (xcd < r ? xcd * (q + 1) : r * (q + 1) + (xcd - r) * q) + j;
}

#define FENCE() asm volatile("" ::: "memory")
#define BARRIER() do { __builtin_amdgcn_s_barrier(); FENCE(); } while (0)

// r12-style k-half LDS swizzle helper for the down kernel (BK=32 rows of 64B)
__device__ __forceinline__ int swz_off(int row, int lane) {
  return row * 64 + ((((lane >> 4)) ^ ((row >> 1) & 3)) << 4);
}

// ---------------- bucketing kernels ----------------
__global__ void k_count(const int* __restrict__ idx, int* __restrict__ counts) {
  int t = blockIdx.x * blockDim.x + threadIdx.x;
  if (t < T_TOK) atomicAdd(&counts[idx[t]], 1);
}

__global__ void k_tilesB(const int* __restrict__ counts, int* __restrict__ offsets,
                         int* __restrict__ tE, int* __restrict__ tB,
                         int* __restrict__ tEnd, int* __restrict__ nT) {
  if (threadIdx.x != 0 || blockIdx.x != 0) return;
  int off = 0, nt = 0;
  for (int e = 0; e < E_EXP; ++e) {
    offsets[e] = off;
    int c = counts[e];
    for (int b = 0; b < c; b += 256) { tE[nt] = e; tB[nt] = off + b; tEnd[nt] = off + c; ++nt; }
    off += c;
  }
  offsets[E_EXP] = off;
  *nT = nt;
}

__global__ void k_scatter(const int* __restrict__ idx, const int* __restrict__ offsets,
                          int* __restrict__ cursor, int* __restrict__ order) {
  int t = blockIdx.x * blockDim.x + threadIdx.x;
  if (t < T_TOK) {
    int e = idx[t];
    int p = offsets[e] + atomicAdd(&cursor[e], 1);
    order[p] = t;
  }
}

// ---------------- bf16 pre-conversion (3 weight tensors, one launch) ----------------
__global__ __launch_bounds__(256) void k_cvt3(const float* __restrict__ s0, const float* __restrict__ s1,
                                              const float* __restrict__ s2, __bf16* __restrict__ d0,
                                              __bf16* __restrict__ d1, __bf16* __restrict__ d2, int n8each) {
  int i = blockIdx.x * blockDim.x + threadIdx.x;
  int seg = i / n8each;
  int j = i - seg * n8each;
  if (seg >= 3) return;
  const float* s = seg == 0 ? s0 : (seg == 1 ? s1 : s2);
  __bf16* d = seg == 0 ? d0 : (seg == 1 ? d1 : d2);
  const float4 p0 = ((const float4*)s)[j * 2];
  const float4 p1 = ((const float4*)s)[j * 2 + 1];
  ((bf16x8*)d)[j] = cvt8(p0, p1);
}

// gather by order + convert x -> xp (bf16, permuted rows)
__global__ __launch_bounds__(128) void k_xperm(const float* __restrict__ x,
                                               const int* __restrict__ order,
                                               __bf16* __restrict__ xp) {
  const int row = blockIdx.x;
  const int tok = order[row];
  const float* s = x + (size_t)tok * H_DIM + threadIdx.x * 8;
  const float4 p0 = ((const float4*)s)[0];
  const float4 p1 = ((const float4*)s)[1];
  *(bf16x8*)(xp + (size_t)row * H_DIM + threadIdx.x * 8) = cvt8(p0, p1);
}

// =====================================================================
// pass 2 (r7-validated, best measured gateup: ~128 us): gate/up GEMM +
// silu*mul -> hp. BM=256 x BN=128 dual-op, BK=64 (full 128B-line staging),
// depth-1 prefetch; 128KB dynamic LDS; 1D grid + XCD-chunk swizzle.
// =====================================================================
__global__ __launch_bounds__(512, 2) void k_gateup7(
    const __bf16* __restrict__ xp, const __bf16* __restrict__ wg, const __bf16* __restrict__ wu,
    const int* __restrict__ tE, const int* __restrict__ tB,
    const int* __restrict__ tEnd, const int* __restrict__ nT, __bf16* __restrict__ hp) {
  const int nwg = *nT * GU_COLS;
  const int id = blockIdx.x;
  if (id >= nwg) return;
  const int wgid = xcd_swizzle(id, nwg);
  const int tile = wgid / GU_COLS;
  const int col = wgid - tile * GU_COLS;
  const int e = tE[tile];
  const int rowbase = tB[tile];
  const int rowEnd = tEnd[tile];
  const int nbase = col * 128;

  extern __shared__ __align__(16) unsigned char smem[];
  unsigned char* smA = smem;          // [2][32768]  256 x 128B
  unsigned char* smG = smem + 65536;  // [2][16384]  128 x 128B
  unsigned char* smU = smem + 98304;  // [2][16384]

  const int tid = threadIdx.x;
  const int lane = tid & 63;
  const int w = tid >> 6;            // 0..7
  const int wm = w & 3, wn = w >> 2; // 4 x 2 wave grid, wave tile 64x64

  const int lr = lane >> 3;
  const int lc = (lane & 7) ^ lr;    // pre-swizzled global 16B chunk
  const __bf16* aS[4]; const __bf16* gS[2]; const __bf16* uS[2];
  int adst[4], gdst[2];
#pragma unroll
  for (int r = 0; r < 4; ++r) { // A: 256 rows in 4 rounds of 64
    const int rt = r * 64 + w * 8 + lr;
    aS[r] = xp + (size_t)(rowbase + rt) * H_DIM + lc * 8;
    adst[r] = rt * 128;
  }
#pragma unroll
  for (int r = 0; r < 2; ++r) { // G/U: 128 rows in 2 rounds of 64
    const int rt = r * 64 + w * 8 + lr;
    gS[r] = wg + ((size_t)e * I_DIM + nbase + rt) * H_DIM + lc * 8;
    uS[r] = wu + ((size_t)e * I_DIM + nbase + rt) * H_DIM + lc * 8;
    gdst[r] = rt * 128;
  }

  f32x4 accg[4][4], accu[4][4];
#pragma unroll
  for (int m = 0; m < 4; ++m)
#pragma unroll
    for (int n = 0; n < 4; ++n)
#pragma unroll
      for (int j = 0; j < 4; ++j) { accg[m][n][j] = 0.f; accu[m][n][j] = 0.f; }

  const int nK = H_DIM / BK; // 16
#pragma unroll
  for (int r = 0; r < 4; ++r) gload16(aS[r], smA + adst[r]);
#pragma unroll
  for (int r = 0; r < 2; ++r) {
    gload16(gS[r], smG + gdst[r]);
    gload16(uS[r], smU + gdst[r]);
  }
  __syncthreads();

  int cur = 0;
  for (int kt = 0; kt < nK; ++kt) {
    if (kt + 1 < nK) { // prefetch next K-tile into other buffer
      const int kof = (kt + 1) * BK;
      const int bA = (cur ^ 1) * 32768, bG = (cur ^ 1) * 16384;
#pragma unroll
      for (int r = 0; r < 4; ++r) gload16(aS[r] + kof, smA + bA + adst[r]);
#pragma unroll
      for (int r = 0; r < 2; ++r) {
        gload16(gS[r] + kof, smG + bG + gdst[r]);
        gload16(uS[r] + kof, smU + bG + gdst[r]);
      }
    }
    const unsigned char* A = smA + cur * 32768;
    const unsigned char* G = smG + cur * 16384;
    const unsigned char* U = smU + cur * 16384;
#pragma unroll
    for (int ks = 0; ks < 2; ++ks) {
      const int kc = ks * 64 + ((lane >> 4) * 16);
      bf16x8 a[4], bg[4], bu[4];
#pragma unroll
      for (int m = 0; m < 4; ++m)
        a[m] = *(const bf16x8*)(A + SWZ(wm * 64 + m * 16 + (lane & 15), kc));
#pragma unroll
      for (int n = 0; n < 4; ++n) {
        const int off = SWZ(wn * 64 + n * 16 + (lane & 15), kc);
        bg[n] = *(const bf16x8*)(G + off);
        bu[n] = *(const bf16x8*)(U + off);
      }
#pragma unroll
      for (int m = 0; m < 4; ++m)
#pragma unroll
        for (int n = 0; n < 4; ++n) {
          accg[m][n] = __builtin_amdgcn_mfma_f32_16x16x32_bf16(a[m], bg[n], accg[m][n], 0, 0, 0);
          accu[m][n] = __builtin_amdgcn_mfma_f32_16x16x32_bf16(a[m], bu[n], accu[m][n], 0, 0, 0);
        }
    }
    __syncthreads();
    cur ^= 1;
  }

  // epilogue: h = silu(g)*u -> hp (bf16, permuted row layout)
#pragma unroll
  for (int m = 0; m < 4; ++m) {
    const int row0 = wm * 64 + m * 16 + (lane >> 4) * 4;
#pragma unroll
    for (int j = 0; j < 4; ++j) {
      const int gr = rowbase + row0 + j;
      if (gr < rowEnd) {
        __bf16* dst = hp + (size_t)gr * I_DIM + nbase;
#pragma unroll
        for (int n = 0; n < 4; ++n) {
          const int c2 = wn * 64 + n * 16 + (lane & 15);
          const float g = accg[m][n][j];
          const float u = accu[m][n][j];
          dst[c2] = (__bf16)(g / (1.f + __expf(-g)) * u);
        }
      }
    }
  }
}

// =====================================================================
// pass 3 (r12/r14-validated): down GEMM, 2-phase counted vmcnt(3).
// BM=256 x BN=128 x BK=64; LDS 96KB.
// =====================================================================
__global__ __launch_bounds__(512) void k_down10(
    const __bf16* __restrict__ hp, const __bf16* __restrict__ wd,
    const int* __restrict__ order, const int* __restrict__ tE, const int* __restrict__ tB,
    const int* __restrict__ tEnd, const int* __restrict__ nT, float* __restrict__ out) {
  const int nwg = *nT * DN_COLS;
  const int id = blockIdx.x;
  if (id >= nwg) return;
  const int wgid = xcd_swizzle(id, nwg);
  const int tile = wgid >> 3;
  const int col = wgid & 7;
  const int e = tE[tile];
  const int rowbase = tB[tile];
  const int rowEnd = tEnd[tile];
  const int nbase = col * 128;

  extern __shared__ __align__(16) unsigned char smem2[];
  unsigned char* smA = smem2;
  unsigned char* smW = smem2 + 65536;

  const int tid = threadIdx.x;
  const int lane = tid & 63;
  const int w = tid >> 6;
  const int wm = w >> 1, wn = w & 1;

  const int srow = tid >> 2;
  const int sch = (tid & 3) ^ ((tid >> 3) & 3);
  const __bf16* aS0 = hp + (size_t)(rowbase + srow) * I_DIM + sch * 8;
  const __bf16* aS1 = aS0 + (size_t)128 * I_DIM;
  const __bf16* wS = wd + ((size_t)e * H_DIM + nbase + srow) * I_DIM + sch * 8;
  const int ldst = tid * 16;

  f32x4 acc[4][4];
#pragma unroll
  for (int m = 0; m < 4; ++m)
#pragma unroll
    for (int n = 0; n < 4; ++n)
#pragma unroll
      for (int j = 0; j < 4; ++j) acc[m][n][j] = 0.f;

  auto STAGE = [&](int t1, int kh) {
    const int b = t1 & 1;
    const size_t ko = (size_t)t1 * 64 + kh * 32;
    gload16(aS0 + ko, smA + (b * 2 + kh) * 16384 + ldst);
    gload16(aS1 + ko, smA + (b * 2 + kh) * 16384 + 8192 + ldst);
    gload16(wS + ko, smW + (b * 2 + kh) * 8192 + ldst);
  };

  auto COMPUTE = [&](int buf, int kh) {
    const unsigned char* A = smA + (buf * 2 + kh) * 16384;
    const unsigned char* W = smW + (buf * 2 + kh) * 8192;
    bf16x8 a[4], b[4];
#pragma unroll
    for (int m = 0; m < 4; ++m)
      a[m] = *(const bf16x8*)(A + swz_off(wm * 64 + m * 16 + (lane & 15), lane));
#pragma unroll
    for (int n = 0; n < 4; ++n)
      b[n] = *(const bf16x8*)(W + swz_off(wn * 64 + n * 16 + (lane & 15), lane));
    __builtin_amdgcn_s_setprio(1);
#pragma unroll
    for (int m = 0; m < 4; ++m)
#pragma unroll
      for (int n = 0; n < 4; ++n)
        acc[m][n] = __builtin_amdgcn_mfma_f32_16x16x32_bf16(a[m], b[n], acc[m][n], 0, 0, 0);
    __builtin_amdgcn_s_setprio(0);
  };

  const int nK = I_DIM / 64; // 44
  STAGE(0, 0);
  STAGE(0, 1);
  asm volatile("s_waitcnt vmcnt(3)" ::: "memory");
  BARRIER();

  for (int t = 0; t < nK; ++t) {
    const int buf = t & 1;
    const bool pf = (t + 1 < nK);
    if (pf) STAGE(t + 1, 0);
    COMPUTE(buf, 0);
    if (pf) asm volatile("s_waitcnt vmcnt(3)" ::: "memory");
    else    asm volatile("s_waitcnt vmcnt(0)" ::: "memory");
    BARRIER();
    if (pf) STAGE(t + 1, 1);
    COMPUTE(buf, 1);
    if (pf) asm volatile("s_waitcnt vmcnt(3)" ::: "memory");
    else    asm volatile("s_waitcnt vmcnt(0)" ::: "memory");
    BARRIER();
  }

#pragma unroll
  for (int m = 0; m < 4; ++m) {
    const int row0 = wm * 64 + m * 16 + ((lane >> 4) << 2);
#pragma unroll
    for (int j = 0; j < 4; ++j) {
      const int gr = rowbase + row0 + j;
      if (gr < rowEnd) {
        const int tok = order[gr];
        float* dst = out + (size_t)tok * H_DIM + nbase;
#pragma unroll
        for (int n = 0; n < 4; ++n) {
          const int c2 = wn * 64 + n * 16 + (lane & 15);
          dst[c2] = acc[m][n][j];
        }
      }
    }
  }
}

// ---------------- launch ----------------
extern "C" void kernel_launch(void* const* d_in, const int* in_sizes, int n_in,
                              void* d_out, int out_size, void* d_ws, size_t ws_size,
                              hipStream_t stream) {
  const float* x = (const float*)d_in[0];
  const int* eidx = (const int*)d_in[1];
  const float* Wg = (const float*)d_in[2];
  const float* Wu = (const float*)d_in[3];
  const float* Wd = (const float*)d_in[4];
  float* out = (float*)d_out;

  char* ws = (char*)d_ws;
  size_t off = 0;
  auto alloc = [&](size_t bytes) -> void* {
    void* p = ws + off;
    off = (off + bytes + 255) & ~(size_t)255;
    return p;
  };
  const size_t TPAD = T_TOK + 256; // tile overreads stay within +256 rows
  __bf16* hp = (__bf16*)alloc(TPAD * I_DIM * sizeof(__bf16));
  int* order = (int*)alloc(T_TOK * sizeof(int));
  int* offsets = (int*)alloc((E_EXP + 1) * sizeof(int));
  int* tE = (int*)alloc(MAXT * sizeof(int));
  int* tB = (int*)alloc(MAXT * sizeof(int));
  int* tEnd = (int*)alloc(MAXT * sizeof(int));
  int* nT = (int*)alloc(sizeof(int));
  int* cc = (int*)alloc(2 * E_EXP * sizeof(int)); // counts | cursor
  int* counts = cc;
  int* cursor = cc + E_EXP;

  const size_t WSZ = (size_t)E_EXP * I_DIM * H_DIM; // elements per weight tensor
  __bf16* xp = (__bf16*)alloc(TPAD * H_DIM * sizeof(__bf16));
  __bf16* wg16 = (__bf16*)alloc(WSZ * sizeof(__bf16));
  __bf16* wu16 = (__bf16*)alloc(WSZ * sizeof(__bf16));
  __bf16* wd16 = (__bf16*)alloc(WSZ * sizeof(__bf16));

  hipFuncSetAttribute((const void*)k_gateup7,
                      hipFuncAttributeMaxDynamicSharedMemorySize, 131072);
  hipFuncSetAttribute((const void*)k_down10,
                      hipFuncAttributeMaxDynamicSharedMemorySize, 98304);

  hipMemsetAsync(cc, 0, 2 * E_EXP * sizeof(int), stream);
  k_count<<<T_TOK / 256, 256, 0, stream>>>(eidx, counts);
  k_tilesB<<<1, 1, 0, stream>>>(counts, offsets, tE, tB, tEnd, nT);
  k_scatter<<<T_TOK / 256, 256, 0, stream>>>(eidx, offsets, cursor, order);

  const int n8 = (int)(WSZ / 8);
  k_cvt3<<<(3 * n8 + 255) / 256, 256, 0, stream>>>(Wg, Wu, Wd, wg16, wu16, wd16, n8);
  k_xperm<<<T_TOK, 128, 0, stream>>>(x, order, xp);

  k_gateup7<<<GU_COLS * MAXT, 512, 131072, stream>>>(xp, wg16, wu16, tE, tB, tEnd, nT, hp);
  k_down10<<<MAXT * DN_COLS, 512, 98304, stream>>>(hp, wd16, order, tE, tB, tEnd, nT, out);
}